// Round 1
// baseline (280.884 us; speedup 1.0000x reference)
//
#include <hip/hip_runtime.h>

// Problem constants (from reference)
#define N_COLS 500000
#define M1 257            // rows in relation
#define B_VECS 8
#define ABS_MAX_F 1023.0f
#define REL_ELEMS ((size_t)M1 * (size_t)N_COLS)   // 128,500,000

// Initialize the 8 "recognized" output slots to 1.0 (true).
// Main kernel will overwrite with 0.0 on the (rare) failure path.
__global__ void am_init_recognized(float* __restrict__ rec) {
    int t = threadIdx.x;
    if (t < B_VECS) rec[t] = 1.0f;
}

// One thread handles 4 adjacent columns. Streams all 257 rows:
// coalesced float4 read from rel_in, apply saturating count-add, float4 write.
__global__ __launch_bounds__(256) void am_main_kernel(
    const float* __restrict__ rel_in,
    const int*   __restrict__ vec_in,
    float*       __restrict__ rel_out,
    float*       __restrict__ rec_out)
{
    int t  = blockIdx.x * blockDim.x + threadIdx.x;
    int j0 = t * 4;
    if (j0 >= N_COLS) return;

    // Load and validate the 8 indices for each of the 4 columns.
    // _validate: (v < 0 || v > 256) -> 256   (int inputs: no NaN possible)
    int idx[B_VECS][4];
    #pragma unroll
    for (int b = 0; b < B_VECS; ++b) {
        int4 v = *reinterpret_cast<const int4*>(vec_in + (size_t)b * N_COLS + j0);
        int vv0 = v.x, vv1 = v.y, vv2 = v.z, vv3 = v.w;
        idx[b][0] = ((unsigned)vv0 > 256u) ? 256 : vv0;
        idx[b][1] = ((unsigned)vv1 > 256u) ? 256 : vv1;
        idx[b][2] = ((unsigned)vv2 > 256u) ? 256 : vv2;
        idx[b][3] = ((unsigned)vv3 > 256u) ? 256 : vv3;
    }

    int bad = 0;  // bit b set => some column for vector b ended <= 0

    const float* in_p  = rel_in  + j0;
    float*       out_p = rel_out + j0;

    #pragma unroll 4
    for (int i = 0; i < M1; ++i) {
        float4 v = *reinterpret_cast<const float4*>(in_p + (size_t)i * N_COLS);
        float vals[4] = {v.x, v.y, v.z, v.w};
        #pragma unroll
        for (int c = 0; c < 4; ++c) {
            int cnt = 0;
            #pragma unroll
            for (int b = 0; b < B_VECS; ++b) cnt += (idx[b][c] == i) ? 1 : 0;
            // Sequential saturating +1 x cnt == min(orig + cnt, 1023)
            // (valid since inputs are in [0, 1023])
            float nv = fminf(vals[c] + (float)cnt, ABS_MAX_F);
            if (cnt > 0) {
                if (nv <= 0.0f) {   // essentially never taken; exactness path
                    #pragma unroll
                    for (int b = 0; b < B_VECS; ++b)
                        if (idx[b][c] == i) bad |= (1 << b);
                }
                vals[c] = nv;
            }
            // cnt == 0: keep original value bit-exact
        }
        float4 o;
        o.x = vals[0]; o.y = vals[1]; o.z = vals[2]; o.w = vals[3];
        *reinterpret_cast<float4*>(out_p + (size_t)i * N_COLS) = o;
    }

    if (bad) {
        #pragma unroll
        for (int b = 0; b < B_VECS; ++b)
            if (bad & (1 << b)) rec_out[b] = 0.0f;  // all writers write 0.0: race-safe
    }
}

extern "C" void kernel_launch(void* const* d_in, const int* in_sizes, int n_in,
                              void* d_out, int out_size, void* d_ws, size_t ws_size,
                              hipStream_t stream) {
    const float* rel = (const float*)d_in[0];   // (257, 500000) float32
    const int*   vec = (const int*)d_in[1];     // (8, 500000) int32
    float* out     = (float*)d_out;             // relation (128.5M) ++ recognized (8)
    float* rec_out = out + REL_ELEMS;

    am_init_recognized<<<1, 64, 0, stream>>>(rec_out);

    int threads = N_COLS / 4;                   // 125,000
    int blocks  = (threads + 255) / 256;        // 489
    am_main_kernel<<<blocks, 256, 0, stream>>>(rel, vec, out, rec_out);
}

// Round 3
// 210.573 us; speedup vs baseline: 1.3339x; 1.3339x over previous
//
#include <hip/hip_runtime.h>

// Problem constants (from reference)
#define N_COLS 500000
#define M1 257            // rows in relation
#define B_VECS 8
#define ABS_MAX_F 1023.0f
#define REL_ELEMS ((size_t)M1 * (size_t)N_COLS)   // 128,500,000
#define ROW_SPLIT 4       // grid.y splits the row loop for TLP

typedef float f32x4 __attribute__((ext_vector_type(4)));  // native vec for nontemporal builtins
typedef int   i32x4 __attribute__((ext_vector_type(4)));

// Initialize the 8 "recognized" output slots to 1.0 (true).
// Main kernel overwrites with 0.0 on the (rare) failure path.
__global__ void am_init_recognized(float* __restrict__ rec) {
    int t = threadIdx.x;
    if (t < B_VECS) rec[t] = 1.0f;
}

// One thread handles 4 adjacent columns x ~64 rows (row chunk = blockIdx.y).
// Coalesced nontemporal float4 read from rel_in, saturating count-add,
// nontemporal float4 write. Vectors (reused across row chunks) stay cached.
__global__ __launch_bounds__(256) void am_main_kernel(
    const float* __restrict__ rel_in,
    const int*   __restrict__ vec_in,
    float*       __restrict__ rel_out,
    float*       __restrict__ rec_out)
{
    int t  = blockIdx.x * blockDim.x + threadIdx.x;
    int j0 = t * 4;
    if (j0 >= N_COLS) return;

    const int chunk = blockIdx.y;
    const int r0 = (chunk * M1) / ROW_SPLIT;        // 0,64,128,192
    const int r1 = ((chunk + 1) * M1) / ROW_SPLIT;  // 64,128,192,257

    // Load and validate the 8 indices for each of the 4 columns.
    // _validate: (v < 0 || v > 256) -> 256   (int inputs: no NaN possible)
    int idx[B_VECS][4];
    #pragma unroll
    for (int b = 0; b < B_VECS; ++b) {
        i32x4 v = *reinterpret_cast<const i32x4*>(vec_in + (size_t)b * N_COLS + j0);
        #pragma unroll
        for (int c = 0; c < 4; ++c)
            idx[b][c] = ((unsigned)v[c] > 256u) ? 256 : v[c];
    }

    int bad = 0;  // bit b set => some column for vector b ended <= 0

    const float* in_p  = rel_in  + j0;
    float*       out_p = rel_out + j0;

    #pragma unroll 4
    for (int i = r0; i < r1; ++i) {
        f32x4 v = __builtin_nontemporal_load(
            reinterpret_cast<const f32x4*>(in_p + (size_t)i * N_COLS));
        #pragma unroll
        for (int c = 0; c < 4; ++c) {
            int cnt = 0;
            #pragma unroll
            for (int b = 0; b < B_VECS; ++b) cnt += (idx[b][c] == i) ? 1 : 0;
            // Sequential saturating +1 x cnt == min(orig + cnt, 1023)
            // (valid since inputs are in [0, 1023])
            float nv = fminf(v[c] + (float)cnt, ABS_MAX_F);
            if (cnt > 0) {
                if (nv <= 0.0f) {   // essentially never taken; exactness path
                    #pragma unroll
                    for (int b = 0; b < B_VECS; ++b)
                        if (idx[b][c] == i) bad |= (1 << b);
                }
                v[c] = nv;
            }
            // cnt == 0: keep original value bit-exact
        }
        __builtin_nontemporal_store(v,
            reinterpret_cast<f32x4*>(out_p + (size_t)i * N_COLS));
    }

    if (bad) {
        #pragma unroll
        for (int b = 0; b < B_VECS; ++b)
            if (bad & (1 << b)) rec_out[b] = 0.0f;  // all writers write 0.0: race-safe
    }
}

extern "C" void kernel_launch(void* const* d_in, const int* in_sizes, int n_in,
                              void* d_out, int out_size, void* d_ws, size_t ws_size,
                              hipStream_t stream) {
    const float* rel = (const float*)d_in[0];   // (257, 500000) float32
    const int*   vec = (const int*)d_in[1];     // (8, 500000) int32
    float* out     = (float*)d_out;             // relation (128.5M) ++ recognized (8)
    float* rec_out = out + REL_ELEMS;

    am_init_recognized<<<1, 64, 0, stream>>>(rec_out);

    int threads = N_COLS / 4;                        // 125,000
    dim3 grid((threads + 255) / 256, ROW_SPLIT);     // 489 x 4 blocks
    am_main_kernel<<<grid, 256, 0, stream>>>(rel, vec, out, rec_out);
}

// Round 4
// 210.206 us; speedup vs baseline: 1.3362x; 1.0017x over previous
//
#include <hip/hip_runtime.h>

// Problem constants (from reference)
#define N_COLS 500000
#define M1 257            // rows in relation
#define B_VECS 8
#define ABS_MAX_F 1023.0f
#define REL_ELEMS ((size_t)M1 * (size_t)N_COLS)   // 128,500,000
#define ROW_SPLIT 4       // grid.y splits the row loop for TLP

typedef float f32x4 __attribute__((ext_vector_type(4)));  // native vec for nontemporal builtins
typedef int   i32x4 __attribute__((ext_vector_type(4)));

// Initialize the 8 "recognized" output slots to 1.0 (true).
// Main kernel overwrites with 0.0 on the (rare) failure path.
__global__ void am_init_recognized(float* __restrict__ rec) {
    int t = threadIdx.x;
    if (t < B_VECS) rec[t] = 1.0f;
}

// One thread handles 4 adjacent columns x ~64 rows (row chunk = blockIdx.y).
// Coalesced nontemporal float4 read from rel_in, saturating count-add,
// nontemporal float4 write. Vectors (reused across row chunks) stay cached.
// __launch_bounds__(256, 8): force VGPR<=64 so 8 waves/SIMD -> whole grid
// (7812 waves) is co-resident in one round (8192 slots).
__global__ __launch_bounds__(256, 8) void am_main_kernel(
    const float* __restrict__ rel_in,
    const int*   __restrict__ vec_in,
    float*       __restrict__ rel_out,
    float*       __restrict__ rec_out)
{
    int t  = blockIdx.x * blockDim.x + threadIdx.x;
    int j0 = t * 4;
    if (j0 >= N_COLS) return;

    const int chunk = blockIdx.y;
    const int r0 = (chunk * M1) / ROW_SPLIT;        // 0,64,128,192
    const int r1 = ((chunk + 1) * M1) / ROW_SPLIT;  // 64,128,192,257

    // Load and validate the 8 indices for each of the 4 columns.
    // _validate: (v < 0 || v > 256) -> 256   (int inputs: no NaN possible)
    int idx[B_VECS][4];
    #pragma unroll
    for (int b = 0; b < B_VECS; ++b) {
        i32x4 v = *reinterpret_cast<const i32x4*>(vec_in + (size_t)b * N_COLS + j0);
        #pragma unroll
        for (int c = 0; c < 4; ++c)
            idx[b][c] = ((unsigned)v[c] > 256u) ? 256 : v[c];
    }

    int bad = 0;  // bit b set => some column for vector b ended <= 0

    const float* in_p  = rel_in  + j0;
    float*       out_p = rel_out + j0;

    #pragma unroll 4
    for (int i = r0; i < r1; ++i) {
        f32x4 v = __builtin_nontemporal_load(
            reinterpret_cast<const f32x4*>(in_p + (size_t)i * N_COLS));
        #pragma unroll
        for (int c = 0; c < 4; ++c) {
            int cnt = 0;
            #pragma unroll
            for (int b = 0; b < B_VECS; ++b) cnt += (idx[b][c] == i) ? 1 : 0;
            // Sequential saturating +1 x cnt == min(orig + cnt, 1023)
            // (valid since inputs are in [0, 1023]). For cnt==0 this is
            // bit-exact identity: v is an integer-valued float <= 1023.
            float nv = fminf(v[c] + (float)cnt, ABS_MAX_F);
            if (__builtin_expect(nv <= 0.0f && cnt > 0, 0)) {
                // essentially never taken; exactness path for `recognized`
                #pragma unroll
                for (int b = 0; b < B_VECS; ++b)
                    if (idx[b][c] == i) bad |= (1 << b);
            }
            v[c] = nv;
        }
        __builtin_nontemporal_store(v,
            reinterpret_cast<f32x4*>(out_p + (size_t)i * N_COLS));
    }

    if (bad) {
        #pragma unroll
        for (int b = 0; b < B_VECS; ++b)
            if (bad & (1 << b)) rec_out[b] = 0.0f;  // all writers write 0.0: race-safe
    }
}

extern "C" void kernel_launch(void* const* d_in, const int* in_sizes, int n_in,
                              void* d_out, int out_size, void* d_ws, size_t ws_size,
                              hipStream_t stream) {
    const float* rel = (const float*)d_in[0];   // (257, 500000) float32
    const int*   vec = (const int*)d_in[1];     // (8, 500000) int32
    float* out     = (float*)d_out;             // relation (128.5M) ++ recognized (8)
    float* rec_out = out + REL_ELEMS;

    am_init_recognized<<<1, 64, 0, stream>>>(rec_out);

    int threads = N_COLS / 4;                        // 125,000
    dim3 grid((threads + 255) / 256, ROW_SPLIT);     // 489 x 4 blocks
    am_main_kernel<<<grid, 256, 0, stream>>>(rel, vec, out, rec_out);
}

// Round 5
// 206.329 us; speedup vs baseline: 1.3613x; 1.0188x over previous
//
#include <hip/hip_runtime.h>

// Problem constants (from reference)
#define N_COLS 500000
#define M1 257            // rows in relation
#define B_VECS 8
#define ABS_MAX_F 1023.0f
#define REL_ELEMS ((size_t)M1 * (size_t)N_COLS)   // 128,500,000
#define ROW_SPLIT 4       // grid.y splits the row loop for TLP

typedef float f32x4 __attribute__((ext_vector_type(4)));  // native vec for nontemporal builtins
typedef int   i32x4 __attribute__((ext_vector_type(4)));

// Initialize the 8 "recognized" output slots to 1.0 (true).
// Main kernel overwrites with 0.0 on the (rare) failure path.
__global__ void am_init_recognized(float* __restrict__ rec) {
    int t = threadIdx.x;
    if (t < B_VECS) rec[t] = 1.0f;
}

// One thread handles 4 adjacent columns x ~64 rows (row chunk = blockIdx.y).
// Hot loop is fully branch-free: NT float4 read -> saturating count-add ->
// NT float4 write, with a 2-op/col running-min tracking the (never-occurring)
// "final value <= 0" condition. Exact `recognized` resolution happens in a
// cold post-loop path that recomputes from global memory.
__global__ __launch_bounds__(256, 8) void am_main_kernel(
    const float* __restrict__ rel_in,
    const int*   __restrict__ vec_in,
    float*       __restrict__ rel_out,
    float*       __restrict__ rec_out)
{
    int t  = blockIdx.x * blockDim.x + threadIdx.x;
    int j0 = t * 4;
    if (j0 >= N_COLS) return;

    const int chunk = blockIdx.y;
    const int r0 = (chunk * M1) / ROW_SPLIT;        // 0,64,128,192
    const int r1 = ((chunk + 1) * M1) / ROW_SPLIT;  // 64,128,192,257

    // Load and validate the 8 indices for each of the 4 columns.
    // _validate: (v < 0 || v > 256) -> 256   (int inputs: no NaN possible)
    int idx[B_VECS][4];
    #pragma unroll
    for (int b = 0; b < B_VECS; ++b) {
        i32x4 v = *reinterpret_cast<const i32x4*>(vec_in + (size_t)b * N_COLS + j0);
        #pragma unroll
        for (int c = 0; c < 4; ++c)
            idx[b][c] = ((unsigned)v[c] > 256u) ? 256 : v[c];
    }

    // Per-column running min of post-update values at incremented cells.
    // Stays 1.0 unless some incremented cell ends <= 0 (never on real data).
    float bmin[4] = {1.0f, 1.0f, 1.0f, 1.0f};

    const float* in_p  = rel_in  + j0;
    float*       out_p = rel_out + j0;

    #pragma unroll 4
    for (int i = r0; i < r1; ++i) {
        f32x4 v = __builtin_nontemporal_load(
            reinterpret_cast<const f32x4*>(in_p + (size_t)i * N_COLS));
        #pragma unroll
        for (int c = 0; c < 4; ++c) {
            int cnt = 0;
            #pragma unroll
            for (int b = 0; b < B_VECS; ++b) cnt += (idx[b][c] == i) ? 1 : 0;
            // Sequential saturating +1 x cnt == min(orig + cnt, 1023)
            // (valid since inputs are in [0, 1023]). For cnt==0 this is
            // bit-exact identity: v is an integer-valued float <= 1023.
            float nv = fminf(v[c] + (float)cnt, ABS_MAX_F);
            bmin[c] = fminf(bmin[c], (cnt > 0) ? nv : 1.0f);  // branch-free flag
            v[c] = nv;
        }
        __builtin_nontemporal_store(v,
            reinterpret_cast<f32x4*>(out_p + (size_t)i * N_COLS));
    }

    // Cold exact path: never taken on valid data (orig >= 0, cnt >= 1 -> nv >= 1).
    if (__builtin_expect(bmin[0] <= 0.0f || bmin[1] <= 0.0f ||
                         bmin[2] <= 0.0f || bmin[3] <= 0.0f, 0)) {
        #pragma unroll
        for (int c = 0; c < 4; ++c) {
            if (bmin[c] > 0.0f) continue;
            for (int b = 0; b < B_VECS; ++b) {
                int row = idx[b][c];
                if (row < r0 || row >= r1) continue;
                float orig = rel_in[(size_t)row * N_COLS + j0 + c];
                int cnt = 0;
                for (int bb = 0; bb < B_VECS; ++bb) cnt += (idx[bb][c] == row) ? 1 : 0;
                float nv = fminf(orig + (float)cnt, ABS_MAX_F);
                if (nv <= 0.0f) rec_out[b] = 0.0f;  // all writers write 0.0: race-safe
            }
        }
    }
}

extern "C" void kernel_launch(void* const* d_in, const int* in_sizes, int n_in,
                              void* d_out, int out_size, void* d_ws, size_t ws_size,
                              hipStream_t stream) {
    const float* rel = (const float*)d_in[0];   // (257, 500000) float32
    const int*   vec = (const int*)d_in[1];     // (8, 500000) int32
    float* out     = (float*)d_out;             // relation (128.5M) ++ recognized (8)
    float* rec_out = out + REL_ELEMS;

    am_init_recognized<<<1, 64, 0, stream>>>(rec_out);

    int threads = N_COLS / 4;                        // 125,000
    dim3 grid((threads + 255) / 256, ROW_SPLIT);     // 489 x 4 blocks
    am_main_kernel<<<grid, 256, 0, stream>>>(rel, vec, out, rec_out);
}